// Round 1
// baseline (1358.890 us; speedup 1.0000x reference)
//
#include <hip/hip_runtime.h>
#include <hip/hip_bf16.h>

#define DIMS 128

// ---------------- CSR build ----------------

__global__ __launch_bounds__(256) void hist_kernel(const int* __restrict__ dst,
                                                   int* __restrict__ deg, int E) {
    int i = blockIdx.x * 256 + threadIdx.x;
    if (i < E) atomicAdd(&deg[dst[i]], 1);
}

__global__ __launch_bounds__(256) void scan_kernel(const int* __restrict__ deg,
                                                   int* __restrict__ row_start, int n) {
    __shared__ int buf[256];
    __shared__ int s_carry;
    if (threadIdx.x == 0) s_carry = 0;
    __syncthreads();
    for (int base = 0; base < n; base += 256) {
        int i = base + threadIdx.x;
        int v = (i < n) ? deg[i] : 0;
        buf[threadIdx.x] = v;
        __syncthreads();
        for (int off = 1; off < 256; off <<= 1) {
            int t = 0;
            if (threadIdx.x >= off) t = buf[threadIdx.x - off];
            __syncthreads();
            buf[threadIdx.x] += t;
            __syncthreads();
        }
        int incl = buf[threadIdx.x];
        if (i < n) row_start[i] = s_carry + incl - v;
        __syncthreads();
        if (threadIdx.x == 255) s_carry += incl;
        __syncthreads();
    }
    if (threadIdx.x == 0) row_start[n] = s_carry;
}

__global__ __launch_bounds__(256) void fill_kernel(const int* __restrict__ src,
                                                   const int* __restrict__ dst,
                                                   const int* __restrict__ row_start,
                                                   int* __restrict__ cursor,
                                                   int* __restrict__ col_idx, int E) {
    int i = blockIdx.x * 256 + threadIdx.x;
    if (i < E) {
        int d = dst[i];
        int pos = atomicAdd(&cursor[d], 1);
        col_idx[row_start[d] + pos] = src[i];
    }
}

__global__ __launch_bounds__(256) void deginv_kernel(const int* __restrict__ deg,
                                                     float* __restrict__ deg_inv, int n) {
    int i = blockIdx.x * 256 + threadIdx.x;
    if (i < n) deg_inv[i] = deg[i] > 0 ? 1.0f / (float)deg[i] : 0.0f;
}

// ---------------- fp32 GEMM: Y = X @ W^T  (X [n,128], W [128,128] row-major) ----------------
// 64-row tile per block, full W transposed in LDS, 4x8 micro-tile per thread.

__global__ __launch_bounds__(256) void gemm128(const float* __restrict__ X,
                                               const float* __restrict__ W,
                                               float* __restrict__ Y, int n) {
    __shared__ float Wt[128][132];  // Wt[k][j] = W[j][k]; pad 132 keeps float4 alignment
    __shared__ float xs[64][36];    // K-chunk of 32, pad 36 (float4-aligned, 2-way-bank max)

    const int tid = threadIdx.x;
    // Load + transpose W into LDS (once per block)
    for (int i = tid; i < 128 * 128; i += 256) {
        int j = i >> 7, k = i & 127;
        Wt[k][j] = W[i];
    }

    const int row0 = blockIdx.x * 64;
    const int tx = tid & 15;   // col group: cols tx*8 .. tx*8+7
    const int ty = tid >> 4;   // row group: rows ty*4 .. ty*4+3
    const int lr = tid >> 2;            // load: row within tile
    const int lk = (tid & 3) * 8;       // load: k-offset within chunk

    float acc[4][8];
#pragma unroll
    for (int r = 0; r < 4; ++r)
#pragma unroll
        for (int c = 0; c < 8; ++c) acc[r][c] = 0.0f;

    for (int k0 = 0; k0 < 128; k0 += 32) {
        __syncthreads();  // covers Wt writes (iter 0) and xs reuse (iters 1+)
        if (row0 + lr < n) {
            const float* src = X + (size_t)(row0 + lr) * DIMS + k0 + lk;
            *(float4*)&xs[lr][lk]     = *(const float4*)src;
            *(float4*)&xs[lr][lk + 4] = *(const float4*)(src + 4);
        } else {
            float4 z = make_float4(0.f, 0.f, 0.f, 0.f);
            *(float4*)&xs[lr][lk]     = z;
            *(float4*)&xs[lr][lk + 4] = z;
        }
        __syncthreads();
#pragma unroll
        for (int kk = 0; kk < 32; ++kk) {
            const int k = k0 + kk;
            float4 b0 = *(const float4*)&Wt[k][tx * 8];
            float4 b1 = *(const float4*)&Wt[k][tx * 8 + 4];
            float b[8] = {b0.x, b0.y, b0.z, b0.w, b1.x, b1.y, b1.z, b1.w};
            float a[4];
#pragma unroll
            for (int r = 0; r < 4; ++r) a[r] = xs[ty * 4 + r][kk];
#pragma unroll
            for (int r = 0; r < 4; ++r)
#pragma unroll
                for (int c = 0; c < 8; ++c) acc[r][c] = fmaf(a[r], b[c], acc[r][c]);
        }
    }

#pragma unroll
    for (int r = 0; r < 4; ++r) {
        int row = row0 + ty * 4 + r;
        if (row < n) {
            float4 o0 = make_float4(acc[r][0], acc[r][1], acc[r][2], acc[r][3]);
            float4 o1 = make_float4(acc[r][4], acc[r][5], acc[r][6], acc[r][7]);
            *(float4*)(Y + (size_t)row * DIMS + tx * 8)     = o0;
            *(float4*)(Y + (size_t)row * DIMS + tx * 8 + 4) = o1;
        }
    }
}

// ---------------- aggregation + fused epilogue ----------------
// One wave per dst node; lane holds dims {2*lane, 2*lane+1}.
// out = deg_inv*sum(yl[src]) + bias + yr; mode 0: relu + identity; mode 1: L2 normalize.

__global__ __launch_bounds__(256) void aggregate_kernel(
    const float* __restrict__ yl, const float* __restrict__ yr,
    const float* __restrict__ bias, const float* __restrict__ identity,
    const int* __restrict__ row_start, const int* __restrict__ col_idx,
    const float* __restrict__ deg_inv, float* __restrict__ out, int n, int mode) {
    const int w = threadIdx.x >> 6;
    const int lane = threadIdx.x & 63;
    const int node = blockIdx.x * 4 + w;
    if (node >= n) return;

    const int s = row_start[node];
    const int e = row_start[node + 1];
    float ax = 0.f, ay = 0.f;
    for (int p = s; p < e; ++p) {
        int c = col_idx[p];
        const float2 v = *(const float2*)(yl + (size_t)c * DIMS + lane * 2);
        ax += v.x;
        ay += v.y;
    }
    const float di = deg_inv[node];
    const float2 b = *(const float2*)(bias + lane * 2);
    const float2 r = *(const float2*)(yr + (size_t)node * DIMS + lane * 2);
    float hx = fmaf(ax, di, b.x) + r.x;
    float hy = fmaf(ay, di, b.y) + r.y;

    if (mode == 0) {
        const float2 idv = *(const float2*)(identity + (size_t)node * DIMS + lane * 2);
        hx = fmaxf(hx, 0.f) + idv.x;
        hy = fmaxf(hy, 0.f) + idv.y;
    } else {
        float ss = hx * hx + hy * hy;
#pragma unroll
        for (int off = 32; off > 0; off >>= 1) ss += __shfl_xor(ss, off);
        float inv = 1.0f / fmaxf(sqrtf(ss), 1e-12f);
        hx *= inv;
        hy *= inv;
    }
    float2 o = make_float2(hx, hy);
    *(float2*)(out + (size_t)node * DIMS + lane * 2) = o;
}

// ---------------- launch ----------------

extern "C" void kernel_launch(void* const* d_in, const int* in_sizes, int n_in,
                              void* d_out, int out_size, void* d_ws, size_t ws_size,
                              hipStream_t stream) {
    const float* x      = (const float*)d_in[0];
    const int*   eidx   = (const int*)d_in[1];
    const float* Wproj  = (const float*)d_in[2];
    const float* W1_l   = (const float*)d_in[3];
    const float* b1     = (const float*)d_in[4];
    const float* W1_r   = (const float*)d_in[5];
    const float* W2_l   = (const float*)d_in[6];
    const float* b2     = (const float*)d_in[7];
    const float* W2_r   = (const float*)d_in[8];
    const float* W3_l   = (const float*)d_in[9];
    const float* b3     = (const float*)d_in[10];
    const float* W3_r   = (const float*)d_in[11];
    float* out = (float*)d_out;

    const int N = in_sizes[0] / DIMS;
    const int E = in_sizes[1] / 2;
    const int* src = eidx;
    const int* dst = eidx + E;

    // workspace partition
    size_t off = 0;
    auto alloc = [&](size_t bytes) {
        void* p = (char*)d_ws + off;
        off += (bytes + 511) & ~(size_t)511;
        return p;
    };
    int*   deg_cnt   = (int*)alloc((size_t)N * 4);
    int*   cursor    = (int*)alloc((size_t)N * 4);
    int*   row_start = (int*)alloc((size_t)(N + 1) * 4);
    float* deg_inv   = (float*)alloc((size_t)N * 4);
    int*   col_idx   = (int*)alloc((size_t)E * 4);
    float* bufA      = (float*)alloc((size_t)N * DIMS * 4);
    float* bufB      = (float*)alloc((size_t)N * DIMS * 4);
    float* bufC      = (float*)alloc((size_t)N * DIMS * 4);
    (void)ws_size;

    hipMemsetAsync(deg_cnt, 0, (size_t)N * 4, stream);
    hipMemsetAsync(cursor, 0, (size_t)N * 4, stream);

    const int egrid = (E + 255) / 256;
    const int ngrid = (N + 255) / 256;
    const int ggrid = (N + 63) / 64;
    const int agrid = (N + 3) / 4;

    hist_kernel<<<egrid, 256, 0, stream>>>(dst, deg_cnt, E);
    scan_kernel<<<1, 256, 0, stream>>>(deg_cnt, row_start, N);
    fill_kernel<<<egrid, 256, 0, stream>>>(src, dst, row_start, cursor, col_idx, E);
    deginv_kernel<<<ngrid, 256, 0, stream>>>(deg_cnt, deg_inv, N);

    // h = x @ Wproj^T  -> bufA
    gemm128<<<ggrid, 256, 0, stream>>>(x, Wproj, bufA, N);

    // layer 1: identity = x, input = bufA
    gemm128<<<ggrid, 256, 0, stream>>>(bufA, W1_l, bufB, N);
    gemm128<<<ggrid, 256, 0, stream>>>(bufA, W1_r, bufC, N);
    aggregate_kernel<<<agrid, 256, 0, stream>>>(bufB, bufC, b1, x, row_start, col_idx,
                                                deg_inv, bufA, N, 0);

    // layer 2: identity = bufA (in-place row-wise update is safe)
    gemm128<<<ggrid, 256, 0, stream>>>(bufA, W2_l, bufB, N);
    gemm128<<<ggrid, 256, 0, stream>>>(bufA, W2_r, bufC, N);
    aggregate_kernel<<<agrid, 256, 0, stream>>>(bufB, bufC, b2, bufA, row_start, col_idx,
                                                deg_inv, bufA, N, 0);

    // layer 3: normalize, write to d_out
    gemm128<<<ggrid, 256, 0, stream>>>(bufA, W3_l, bufB, N);
    gemm128<<<ggrid, 256, 0, stream>>>(bufA, W3_r, bufC, N);
    aggregate_kernel<<<agrid, 256, 0, stream>>>(bufB, bufC, b3, x, row_start, col_idx,
                                                deg_inv, out, N, 1);
}

// Round 2
// 942.269 us; speedup vs baseline: 1.4421x; 1.4421x over previous
//
#include <hip/hip_runtime.h>
#include <hip/hip_bf16.h>

#define DIMS 128
#define SCAN_B 1024  // elements per scan block (256 threads x 4)

// ---------------- CSR build ----------------

__global__ __launch_bounds__(256) void hist_kernel(const int* __restrict__ dst,
                                                   int* __restrict__ deg, int E) {
    int i = blockIdx.x * 256 + threadIdx.x;
    if (i < E) atomicAdd(&deg[dst[i]], 1);
}

// hierarchical scan, stage 1: per-block sums (1024 elems / block)
__global__ __launch_bounds__(256) void scan_reduce(const int* __restrict__ deg,
                                                   int* __restrict__ bsum, int n) {
    __shared__ int s[256];
    const int t = threadIdx.x;
    const int base = blockIdx.x * SCAN_B;
    int v = 0;
#pragma unroll
    for (int j = 0; j < 4; ++j) {
        int i = base + t * 4 + j;
        if (i < n) v += deg[i];
    }
    s[t] = v;
    __syncthreads();
    for (int off = 128; off > 0; off >>= 1) {
        if (t < off) s[t] += s[t + off];
        __syncthreads();
    }
    if (t == 0) bsum[blockIdx.x] = s[0];
}

// stage 2: exclusive scan of block sums (nb <= 256), single block
__global__ __launch_bounds__(256) void scan_bsum(int* __restrict__ bsum, int nb) {
    __shared__ int s[256];
    const int t = threadIdx.x;
    int v = (t < nb) ? bsum[t] : 0;
    s[t] = v;
    __syncthreads();
    for (int off = 1; off < 256; off <<= 1) {
        int u = (t >= off) ? s[t - off] : 0;
        __syncthreads();
        s[t] += u;
        __syncthreads();
    }
    if (t < nb) bsum[t] = s[t] - v;  // exclusive
}

// stage 3: per-block exclusive scan + block offset -> row_start
__global__ __launch_bounds__(256) void scan_final(const int* __restrict__ deg,
                                                  const int* __restrict__ bsum,
                                                  int* __restrict__ row_start, int n) {
    __shared__ int s[256];
    const int t = threadIdx.x;
    const int base = blockIdx.x * SCAN_B;
    int loc[4];
    int v = 0;
#pragma unroll
    for (int j = 0; j < 4; ++j) {
        int i = base + t * 4 + j;
        loc[j] = (i < n) ? deg[i] : 0;
        v += loc[j];
    }
    s[t] = v;
    __syncthreads();
    for (int off = 1; off < 256; off <<= 1) {
        int u = (t >= off) ? s[t - off] : 0;
        __syncthreads();
        s[t] += u;
        __syncthreads();
    }
    int excl = bsum[blockIdx.x] + s[t] - v;  // exclusive start for this thread's run
#pragma unroll
    for (int j = 0; j < 4; ++j) {
        int i = base + t * 4 + j;
        if (i < n) row_start[i] = excl;
        excl += loc[j];
        if (i == n - 1) row_start[n] = excl;
    }
}

__global__ __launch_bounds__(256) void fill_kernel(const int* __restrict__ src,
                                                   const int* __restrict__ dst,
                                                   const int* __restrict__ row_start,
                                                   int* __restrict__ cursor,
                                                   int* __restrict__ col_idx, int E) {
    int i = blockIdx.x * 256 + threadIdx.x;
    if (i < E) {
        int d = dst[i];
        int pos = atomicAdd(&cursor[d], 1);
        col_idx[row_start[d] + pos] = src[i];
    }
}

__global__ __launch_bounds__(256) void deginv_kernel(const int* __restrict__ deg,
                                                     float* __restrict__ deg_inv, int n) {
    int i = blockIdx.x * 256 + threadIdx.x;
    if (i < n) deg_inv[i] = deg[i] > 0 ? 1.0f / (float)deg[i] : 0.0f;
}

// ---------------- fp32 GEMM: Y = X @ W^T  (X [n,128], W [128,128] row-major) ----------------
// 64-row tile per block, full W transposed in LDS, 4x8 micro-tile per thread.

__global__ __launch_bounds__(256) void gemm128(const float* __restrict__ X,
                                               const float* __restrict__ W,
                                               float* __restrict__ Y, int n) {
    __shared__ float Wt[128][132];  // Wt[k][j] = W[j][k]; pad 132 keeps float4 alignment
    __shared__ float xs[64][36];    // K-chunk of 32, pad 36 (float4-aligned, 2-way-bank max)

    const int tid = threadIdx.x;
    // Load + transpose W into LDS (once per block)
    for (int i = tid; i < 128 * 128; i += 256) {
        int j = i >> 7, k = i & 127;
        Wt[k][j] = W[i];
    }

    const int row0 = blockIdx.x * 64;
    const int tx = tid & 15;   // col group: cols tx*8 .. tx*8+7
    const int ty = tid >> 4;   // row group: rows ty*4 .. ty*4+3
    const int lr = tid >> 2;            // load: row within tile
    const int lk = (tid & 3) * 8;       // load: k-offset within chunk

    float acc[4][8];
#pragma unroll
    for (int r = 0; r < 4; ++r)
#pragma unroll
        for (int c = 0; c < 8; ++c) acc[r][c] = 0.0f;

    for (int k0 = 0; k0 < 128; k0 += 32) {
        __syncthreads();  // covers Wt writes (iter 0) and xs reuse (iters 1+)
        if (row0 + lr < n) {
            const float* src = X + (size_t)(row0 + lr) * DIMS + k0 + lk;
            *(float4*)&xs[lr][lk]     = *(const float4*)src;
            *(float4*)&xs[lr][lk + 4] = *(const float4*)(src + 4);
        } else {
            float4 z = make_float4(0.f, 0.f, 0.f, 0.f);
            *(float4*)&xs[lr][lk]     = z;
            *(float4*)&xs[lr][lk + 4] = z;
        }
        __syncthreads();
#pragma unroll
        for (int kk = 0; kk < 32; ++kk) {
            const int k = k0 + kk;
            float4 b0 = *(const float4*)&Wt[k][tx * 8];
            float4 b1 = *(const float4*)&Wt[k][tx * 8 + 4];
            float b[8] = {b0.x, b0.y, b0.z, b0.w, b1.x, b1.y, b1.z, b1.w};
            float a[4];
#pragma unroll
            for (int r = 0; r < 4; ++r) a[r] = xs[ty * 4 + r][kk];
#pragma unroll
            for (int r = 0; r < 4; ++r)
#pragma unroll
                for (int c = 0; c < 8; ++c) acc[r][c] = fmaf(a[r], b[c], acc[r][c]);
        }
    }

#pragma unroll
    for (int r = 0; r < 4; ++r) {
        int row = row0 + ty * 4 + r;
        if (row < n) {
            float4 o0 = make_float4(acc[r][0], acc[r][1], acc[r][2], acc[r][3]);
            float4 o1 = make_float4(acc[r][4], acc[r][5], acc[r][6], acc[r][7]);
            *(float4*)(Y + (size_t)row * DIMS + tx * 8)     = o0;
            *(float4*)(Y + (size_t)row * DIMS + tx * 8 + 4) = o1;
        }
    }
}

// ---------------- aggregation + fused epilogue ----------------
// One wave per dst node; lane holds dims {2*lane, 2*lane+1}.
// out = deg_inv*sum(yl[src]) + bias + yr; mode 0: relu + identity; mode 1: L2 normalize.

__global__ __launch_bounds__(256) void aggregate_kernel(
    const float* __restrict__ yl, const float* __restrict__ yr,
    const float* __restrict__ bias, const float* __restrict__ identity,
    const int* __restrict__ row_start, const int* __restrict__ col_idx,
    const float* __restrict__ deg_inv, float* __restrict__ out, int n, int mode) {
    const int w = threadIdx.x >> 6;
    const int lane = threadIdx.x & 63;
    const int node = blockIdx.x * 4 + w;
    if (node >= n) return;

    const int s = row_start[node];
    const int e = row_start[node + 1];
    float ax = 0.f, ay = 0.f;
    for (int p = s; p < e; ++p) {
        int c = col_idx[p];
        const float2 v = *(const float2*)(yl + (size_t)c * DIMS + lane * 2);
        ax += v.x;
        ay += v.y;
    }
    const float di = deg_inv[node];
    const float2 b = *(const float2*)(bias + lane * 2);
    const float2 r = *(const float2*)(yr + (size_t)node * DIMS + lane * 2);
    float hx = fmaf(ax, di, b.x) + r.x;
    float hy = fmaf(ay, di, b.y) + r.y;

    if (mode == 0) {
        const float2 idv = *(const float2*)(identity + (size_t)node * DIMS + lane * 2);
        hx = fmaxf(hx, 0.f) + idv.x;
        hy = fmaxf(hy, 0.f) + idv.y;
    } else {
        float ss = hx * hx + hy * hy;
#pragma unroll
        for (int off = 32; off > 0; off >>= 1) ss += __shfl_xor(ss, off);
        float inv = 1.0f / fmaxf(sqrtf(ss), 1e-12f);
        hx *= inv;
        hy *= inv;
    }
    float2 o = make_float2(hx, hy);
    *(float2*)(out + (size_t)node * DIMS + lane * 2) = o;
}

// ---------------- launch ----------------

extern "C" void kernel_launch(void* const* d_in, const int* in_sizes, int n_in,
                              void* d_out, int out_size, void* d_ws, size_t ws_size,
                              hipStream_t stream) {
    const float* x      = (const float*)d_in[0];
    const int*   eidx   = (const int*)d_in[1];
    const float* Wproj  = (const float*)d_in[2];
    const float* W1_l   = (const float*)d_in[3];
    const float* b1     = (const float*)d_in[4];
    const float* W1_r   = (const float*)d_in[5];
    const float* W2_l   = (const float*)d_in[6];
    const float* b2     = (const float*)d_in[7];
    const float* W2_r   = (const float*)d_in[8];
    const float* W3_l   = (const float*)d_in[9];
    const float* b3     = (const float*)d_in[10];
    const float* W3_r   = (const float*)d_in[11];
    float* out = (float*)d_out;

    const int N = in_sizes[0] / DIMS;
    const int E = in_sizes[1] / 2;
    const int* src = eidx;
    const int* dst = eidx + E;

    // workspace partition
    size_t off = 0;
    auto alloc = [&](size_t bytes) {
        void* p = (char*)d_ws + off;
        off += (bytes + 511) & ~(size_t)511;
        return p;
    };
    int*   deg_cnt   = (int*)alloc((size_t)N * 4);
    int*   cursor    = (int*)alloc((size_t)N * 4);
    int*   row_start = (int*)alloc((size_t)(N + 1) * 4);
    float* deg_inv   = (float*)alloc((size_t)N * 4);
    int*   col_idx   = (int*)alloc((size_t)E * 4);
    int*   bsum      = (int*)alloc((size_t)1024 * 4);
    float* bufA      = (float*)alloc((size_t)N * DIMS * 4);
    float* bufB      = (float*)alloc((size_t)N * DIMS * 4);
    float* bufC      = (float*)alloc((size_t)N * DIMS * 4);
    (void)ws_size;

    hipMemsetAsync(deg_cnt, 0, (size_t)N * 4, stream);
    hipMemsetAsync(cursor, 0, (size_t)N * 4, stream);

    const int egrid = (E + 255) / 256;
    const int ngrid = (N + 255) / 256;
    const int sgrid = (N + SCAN_B - 1) / SCAN_B;  // 98 blocks for N=100k
    const int ggrid = (N + 63) / 64;
    const int agrid = (N + 3) / 4;

    hist_kernel<<<egrid, 256, 0, stream>>>(dst, deg_cnt, E);
    scan_reduce<<<sgrid, 256, 0, stream>>>(deg_cnt, bsum, N);
    scan_bsum<<<1, 256, 0, stream>>>(bsum, sgrid);
    scan_final<<<sgrid, 256, 0, stream>>>(deg_cnt, bsum, row_start, N);
    fill_kernel<<<egrid, 256, 0, stream>>>(src, dst, row_start, cursor, col_idx, E);
    deginv_kernel<<<ngrid, 256, 0, stream>>>(deg_cnt, deg_inv, N);

    // h = x @ Wproj^T  -> bufA
    gemm128<<<ggrid, 256, 0, stream>>>(x, Wproj, bufA, N);

    // layer 1: identity = x, input = bufA
    gemm128<<<ggrid, 256, 0, stream>>>(bufA, W1_l, bufB, N);
    gemm128<<<ggrid, 256, 0, stream>>>(bufA, W1_r, bufC, N);
    aggregate_kernel<<<agrid, 256, 0, stream>>>(bufB, bufC, b1, x, row_start, col_idx,
                                                deg_inv, bufA, N, 0);

    // layer 2: identity = bufA (in-place row-wise update is safe)
    gemm128<<<ggrid, 256, 0, stream>>>(bufA, W2_l, bufB, N);
    gemm128<<<ggrid, 256, 0, stream>>>(bufA, W2_r, bufC, N);
    aggregate_kernel<<<agrid, 256, 0, stream>>>(bufB, bufC, b2, bufA, row_start, col_idx,
                                                deg_inv, bufA, N, 0);

    // layer 3: normalize, write to d_out
    gemm128<<<ggrid, 256, 0, stream>>>(bufA, W3_l, bufB, N);
    gemm128<<<ggrid, 256, 0, stream>>>(bufA, W3_r, bufC, N);
    aggregate_kernel<<<agrid, 256, 0, stream>>>(bufB, bufC, b3, x, row_start, col_idx,
                                                deg_inv, out, N, 1);
}

// Round 4
// 555.977 us; speedup vs baseline: 2.4441x; 1.6948x over previous
//
#include <hip/hip_runtime.h>

typedef unsigned int uint;
typedef unsigned short ushort;
typedef float f32x4 __attribute__((ext_vector_type(4)));
typedef short short8 __attribute__((ext_vector_type(8)));

#define DIMS 128
#define SCAN_B 1024

__device__ __forceinline__ ushort f2bf(float f) {
    uint u = __builtin_bit_cast(uint, f);
    u += 0x7fffu + ((u >> 16) & 1u);  // RNE
    return (ushort)(u >> 16);
}
__device__ __forceinline__ float bf2f(uint h) {
    uint u = h << 16;
    return __builtin_bit_cast(float, u);
}

// ---------------- CSR build ----------------

__global__ __launch_bounds__(256) void hist_kernel(const int* __restrict__ dst,
                                                   int* __restrict__ deg, int E) {
    int i = blockIdx.x * 256 + threadIdx.x;
    if (i < E) atomicAdd(&deg[dst[i]], 1);
}

__global__ __launch_bounds__(256) void scan_reduce(const int* __restrict__ deg,
                                                   int* __restrict__ bsum, int n) {
    __shared__ int s[256];
    const int t = threadIdx.x;
    const int base = blockIdx.x * SCAN_B;
    int v = 0;
#pragma unroll
    for (int j = 0; j < 4; ++j) {
        int i = base + t * 4 + j;
        if (i < n) v += deg[i];
    }
    s[t] = v;
    __syncthreads();
    for (int off = 128; off > 0; off >>= 1) {
        if (t < off) s[t] += s[t + off];
        __syncthreads();
    }
    if (t == 0) bsum[blockIdx.x] = s[0];
}

__global__ __launch_bounds__(256) void scan_bsum(int* __restrict__ bsum, int nb) {
    __shared__ int s[256];
    const int t = threadIdx.x;
    int v = (t < nb) ? bsum[t] : 0;
    s[t] = v;
    __syncthreads();
    for (int off = 1; off < 256; off <<= 1) {
        int u = (t >= off) ? s[t - off] : 0;
        __syncthreads();
        s[t] += u;
        __syncthreads();
    }
    if (t < nb) bsum[t] = s[t] - v;
}

__global__ __launch_bounds__(256) void scan_final(const int* __restrict__ deg,
                                                  const int* __restrict__ bsum,
                                                  int* __restrict__ row_start, int n) {
    __shared__ int s[256];
    const int t = threadIdx.x;
    const int base = blockIdx.x * SCAN_B;
    int loc[4];
    int v = 0;
#pragma unroll
    for (int j = 0; j < 4; ++j) {
        int i = base + t * 4 + j;
        loc[j] = (i < n) ? deg[i] : 0;
        v += loc[j];
    }
    s[t] = v;
    __syncthreads();
    for (int off = 1; off < 256; off <<= 1) {
        int u = (t >= off) ? s[t - off] : 0;
        __syncthreads();
        s[t] += u;
        __syncthreads();
    }
    int excl = bsum[blockIdx.x] + s[t] - v;
#pragma unroll
    for (int j = 0; j < 4; ++j) {
        int i = base + t * 4 + j;
        if (i < n) row_start[i] = excl;
        excl += loc[j];
        if (i == n - 1) row_start[n] = excl;
    }
}

__global__ __launch_bounds__(256) void fill_kernel(const int* __restrict__ src,
                                                   const int* __restrict__ dst,
                                                   const int* __restrict__ row_start,
                                                   int* __restrict__ cursor,
                                                   int* __restrict__ col_idx, int E) {
    int i = blockIdx.x * 256 + threadIdx.x;
    if (i < E) {
        int d = dst[i];
        int pos = atomicAdd(&cursor[d], 1);
        col_idx[row_start[d] + pos] = src[i];
    }
}

__global__ __launch_bounds__(256) void deginv_kernel(const int* __restrict__ deg,
                                                     float* __restrict__ deg_inv, int n) {
    int i = blockIdx.x * 256 + threadIdx.x;
    if (i < n) deg_inv[i] = deg[i] > 0 ? 1.0f / (float)deg[i] : 0.0f;
}

// ---------------- bf16 MFMA GEMM: Ya = X@Wa^T [, Yb = X@Wb^T] ----------------
// Block: 256 thr / 4 waves, 64 rows. W staged in LDS in fragment-linear order
// (group g = s*32 + nt*4 + c, 1024 B per group, lane-contiguous 16 B slots →
// conflict-free ds_read_b128 with immediate offsets). A-frags global->reg.
// MFMA 16x16x32 bf16; A and B use identical (lane,slot)->k placement so any
// hw k-permutation cancels. C/D: col=lane&15, row=(lane>>4)*4+reg (verified map).

template <int ABF16, int DUAL>
__global__ __launch_bounds__(256) void gemm_mfma(const void* __restrict__ Xv,
                                                 const float* __restrict__ Wa,
                                                 const float* __restrict__ Wb,
                                                 ushort* __restrict__ Ya,
                                                 ushort* __restrict__ Yb, int n) {
    __shared__ ushort wlds[(DUAL ? 2 : 1) * 16384];

    const int t = threadIdx.x;
    const int l = t & 63;
    const int w = t >> 6;
    const int kg = (l >> 4);        // k-group 0..3
    const int m15 = l & 15;

    // ---- stage W (fragment-linear) ----
    const int NITER = DUAL ? 16 : 8;
#pragma unroll
    for (int it = 0; it < NITER; ++it) {
        int g = it * 4 + w;                 // group id 0..(NMAT*32-1)
        int s = g >> 5;
        int nt = (g >> 2) & 7;
        int c = g & 3;
        int r = nt * 16 + m15;
        int k0 = c * 32 + kg * 8;
        const float* W = (DUAL && s) ? Wb : Wa;
        f32x4 f0 = *(const f32x4*)(W + r * DIMS + k0);
        f32x4 f1 = *(const f32x4*)(W + r * DIMS + k0 + 4);
        short8 v;
        v[0] = (short)f2bf(f0[0]); v[1] = (short)f2bf(f0[1]);
        v[2] = (short)f2bf(f0[2]); v[3] = (short)f2bf(f0[3]);
        v[4] = (short)f2bf(f1[0]); v[5] = (short)f2bf(f1[1]);
        v[6] = (short)f2bf(f1[2]); v[7] = (short)f2bf(f1[3]);
        *(short8*)((char*)wlds + g * 1024 + l * 16) = v;
    }

    // ---- A fragments: global -> reg ----
    const int row0 = blockIdx.x * 64;
    const int arow = row0 + w * 16 + m15;
    short8 af[4];
    if (arow < n) {
#pragma unroll
        for (int c = 0; c < 4; ++c) {
            if (ABF16) {
                const ushort* X = (const ushort*)Xv;
                af[c] = *(const short8*)(X + (size_t)arow * DIMS + c * 32 + kg * 8);
            } else {
                const float* X = (const float*)Xv;
                f32x4 f0 = *(const f32x4*)(X + (size_t)arow * DIMS + c * 32 + kg * 8);
                f32x4 f1 = *(const f32x4*)(X + (size_t)arow * DIMS + c * 32 + kg * 8 + 4);
                short8 v;
                v[0] = (short)f2bf(f0[0]); v[1] = (short)f2bf(f0[1]);
                v[2] = (short)f2bf(f0[2]); v[3] = (short)f2bf(f0[3]);
                v[4] = (short)f2bf(f1[0]); v[5] = (short)f2bf(f1[1]);
                v[6] = (short)f2bf(f1[2]); v[7] = (short)f2bf(f1[3]);
                af[c] = v;
            }
        }
    } else {
#pragma unroll
        for (int c = 0; c < 4; ++c) af[c] = (short8){};
    }

    __syncthreads();

    // ---- MFMA main loop ----
    f32x4 accA[8] = {};
    f32x4 accB[8] = {};
#pragma unroll
    for (int c = 0; c < 4; ++c) {
#pragma unroll
        for (int nt = 0; nt < 8; ++nt) {
            short8 bA = *(const short8*)((const char*)wlds + (nt * 4 + c) * 1024 + l * 16);
            accA[nt] = __builtin_amdgcn_mfma_f32_16x16x32_bf16(af[c], bA, accA[nt], 0, 0, 0);
            if (DUAL) {
                short8 bB = *(const short8*)((const char*)wlds + (32 + nt * 4 + c) * 1024 + l * 16);
                accB[nt] = __builtin_amdgcn_mfma_f32_16x16x32_bf16(af[c], bB, accB[nt], 0, 0, 0);
            }
        }
    }

    // ---- store (bf16) ----
    const int r0 = w * 16 + (l >> 4) * 4;
#pragma unroll
    for (int nt = 0; nt < 8; ++nt) {
#pragma unroll
        for (int j = 0; j < 4; ++j) {
            int row = row0 + r0 + j;
            if (row < n) {
                Ya[(size_t)row * DIMS + nt * 16 + m15] = f2bf(accA[nt][j]);
                if (DUAL) Yb[(size_t)row * DIMS + nt * 16 + m15] = f2bf(accB[nt][j]);
            }
        }
    }
}

// ---------------- aggregation + fused epilogue (bf16 in) ----------------
// One wave per dst node; lane holds dims {2*lane, 2*lane+1}.
// h = deg_inv*sum(yl[src]) + bias + yr; mode 0: relu + identity; mode 1: L2 norm.
// Writes fp32 (if out_f32) and/or bf16 (if out_bf16).

__global__ __launch_bounds__(256) void aggregate_kernel(
    const ushort* __restrict__ yl, const ushort* __restrict__ yr,
    const float* __restrict__ bias, const float* __restrict__ identity,
    const int* __restrict__ row_start, const int* __restrict__ col_idx,
    const float* __restrict__ deg_inv, float* __restrict__ out_f32,
    ushort* __restrict__ out_bf16, int n, int mode) {
    const int wv = threadIdx.x >> 6;
    const int lane = threadIdx.x & 63;
    const int node = blockIdx.x * 4 + wv;
    if (node >= n) return;

    const int s = row_start[node];
    const int e = row_start[node + 1];
    const int cnt = e - s;
    float ax = 0.f, ay = 0.f;
    for (int p0 = 0; p0 < cnt; p0 += 64) {
        int m = cnt - p0;
        if (m > 64) m = 64;
        int cv = (p0 + lane < cnt) ? col_idx[s + p0 + lane] : 0;
        for (int j = 0; j < m; ++j) {
            int c = __shfl(cv, j);
            uint v = *(const uint*)(yl + (size_t)c * DIMS + lane * 2);
            ax += bf2f(v & 0xffffu);
            ay += bf2f(v >> 16);
        }
    }
    const float di = deg_inv[node];
    const float2 b = *(const float2*)(bias + lane * 2);
    const uint rv = *(const uint*)(yr + (size_t)node * DIMS + lane * 2);
    float hx = fmaf(ax, di, b.x) + bf2f(rv & 0xffffu);
    float hy = fmaf(ay, di, b.y) + bf2f(rv >> 16);

    if (mode == 0) {
        const float2 idv = *(const float2*)(identity + (size_t)node * DIMS + lane * 2);
        hx = fmaxf(hx, 0.f) + idv.x;
        hy = fmaxf(hy, 0.f) + idv.y;
    } else {
        float ss = hx * hx + hy * hy;
#pragma unroll
        for (int off = 32; off > 0; off >>= 1) ss += __shfl_xor(ss, off);
        float inv = 1.0f / fmaxf(sqrtf(ss), 1e-12f);
        hx *= inv;
        hy *= inv;
    }
    if (out_f32) *(float2*)(out_f32 + (size_t)node * DIMS + lane * 2) = make_float2(hx, hy);
    if (out_bf16) {
        uint u = ((uint)f2bf(hy) << 16) | (uint)f2bf(hx);
        *(uint*)(out_bf16 + (size_t)node * DIMS + lane * 2) = u;
    }
}

// ---------------- launch ----------------

extern "C" void kernel_launch(void* const* d_in, const int* in_sizes, int n_in,
                              void* d_out, int out_size, void* d_ws, size_t ws_size,
                              hipStream_t stream) {
    const float* x     = (const float*)d_in[0];
    const int*   eidx  = (const int*)d_in[1];
    const float* Wproj = (const float*)d_in[2];
    const float* W1_l  = (const float*)d_in[3];
    const float* b1    = (const float*)d_in[4];
    const float* W1_r  = (const float*)d_in[5];
    const float* W2_l  = (const float*)d_in[6];
    const float* b2    = (const float*)d_in[7];
    const float* W2_r  = (const float*)d_in[8];
    const float* W3_l  = (const float*)d_in[9];
    const float* b3    = (const float*)d_in[10];
    const float* W3_r  = (const float*)d_in[11];
    float* out = (float*)d_out;

    const int N = in_sizes[0] / DIMS;
    const int E = in_sizes[1] / 2;
    const int* src = eidx;
    const int* dst = eidx + E;

    size_t off = 0;
    auto alloc = [&](size_t bytes) {
        void* p = (char*)d_ws + off;
        off += (bytes + 511) & ~(size_t)511;
        return p;
    };
    int*    deg_cnt   = (int*)alloc((size_t)N * 4);
    int*    cursor    = (int*)alloc((size_t)N * 4);
    int*    row_start = (int*)alloc((size_t)(N + 1) * 4);
    float*  deg_inv   = (float*)alloc((size_t)N * 4);
    int*    col_idx   = (int*)alloc((size_t)E * 4);
    int*    bsum      = (int*)alloc((size_t)1024 * 4);
    ushort* h0b       = (ushort*)alloc((size_t)N * DIMS * 2);  // Wproj out; reused as h2b
    ushort* h1b       = (ushort*)alloc((size_t)N * DIMS * 2);
    ushort* ylb       = (ushort*)alloc((size_t)N * DIMS * 2);
    ushort* yrb       = (ushort*)alloc((size_t)N * DIMS * 2);
    float*  h1f       = (float*)alloc((size_t)N * DIMS * 4);
    ushort* h2b       = h0b;
    (void)ws_size;

    hipMemsetAsync(deg_cnt, 0, (size_t)N * 4, stream);
    hipMemsetAsync(cursor, 0, (size_t)N * 4, stream);

    const int egrid = (E + 255) / 256;
    const int ngrid = (N + 255) / 256;
    const int sgrid = (N + SCAN_B - 1) / SCAN_B;
    const int ggrid = (N + 63) / 64;
    const int agrid = (N + 3) / 4;

    hist_kernel<<<egrid, 256, 0, stream>>>(dst, deg_cnt, E);
    scan_reduce<<<sgrid, 256, 0, stream>>>(deg_cnt, bsum, N);
    scan_bsum<<<1, 256, 0, stream>>>(bsum, sgrid);
    scan_final<<<sgrid, 256, 0, stream>>>(deg_cnt, bsum, row_start, N);
    fill_kernel<<<egrid, 256, 0, stream>>>(src, dst, row_start, cursor, col_idx, E);
    deginv_kernel<<<ngrid, 256, 0, stream>>>(deg_cnt, deg_inv, N);

    // h0 = x @ Wproj^T (fp32 A, single output, bf16 out)
    gemm_mfma<0, 0><<<ggrid, 256, 0, stream>>>(x, Wproj, nullptr, h0b, nullptr, N);

    // layer 1
    gemm_mfma<1, 1><<<ggrid, 256, 0, stream>>>(h0b, W1_l, W1_r, ylb, yrb, N);
    aggregate_kernel<<<agrid, 256, 0, stream>>>(ylb, yrb, b1, x, row_start, col_idx,
                                                deg_inv, h1f, h1b, N, 0);

    // layer 2 (identity = h1f; fp32 out not needed downstream)
    gemm_mfma<1, 1><<<ggrid, 256, 0, stream>>>(h1b, W2_l, W2_r, ylb, yrb, N);
    aggregate_kernel<<<agrid, 256, 0, stream>>>(ylb, yrb, b2, h1f, row_start, col_idx,
                                                deg_inv, nullptr, h2b, N, 0);

    // layer 3 (L2 normalize -> d_out fp32)
    gemm_mfma<1, 1><<<ggrid, 256, 0, stream>>>(h2b, W3_l, W3_r, ylb, yrb, N);
    aggregate_kernel<<<agrid, 256, 0, stream>>>(ylb, yrb, b3, nullptr, row_start, col_idx,
                                                deg_inv, out, nullptr, N, 1);
}

// Round 5
// 437.099 us; speedup vs baseline: 3.1089x; 1.2720x over previous
//
#include <hip/hip_runtime.h>

typedef unsigned int uint;
typedef unsigned short ushort;
typedef float f32x4 __attribute__((ext_vector_type(4)));
typedef short short8 __attribute__((ext_vector_type(8)));

#define DIMS 128
#define SCAN_B 1024

__device__ __forceinline__ ushort f2bf(float f) {
    uint u = __builtin_bit_cast(uint, f);
    u += 0x7fffu + ((u >> 16) & 1u);  // RNE
    return (ushort)(u >> 16);
}
__device__ __forceinline__ float bf2f(ushort h) {
    uint u = (uint)h << 16;
    return __builtin_bit_cast(float, u);
}

// ---------------- CSR build ----------------

__global__ __launch_bounds__(256) void hist_kernel(const int* __restrict__ dst,
                                                   int* __restrict__ deg, int E) {
    int i = blockIdx.x * 256 + threadIdx.x;
    if (i < E) atomicAdd(&deg[dst[i]], 1);
}

__global__ __launch_bounds__(256) void scan_reduce(const int* __restrict__ deg,
                                                   int* __restrict__ bsum, int n) {
    __shared__ int s[256];
    const int t = threadIdx.x;
    const int base = blockIdx.x * SCAN_B;
    int v = 0;
#pragma unroll
    for (int j = 0; j < 4; ++j) {
        int i = base + t * 4 + j;
        if (i < n) v += deg[i];
    }
    s[t] = v;
    __syncthreads();
    for (int off = 128; off > 0; off >>= 1) {
        if (t < off) s[t] += s[t + off];
        __syncthreads();
    }
    if (t == 0) bsum[blockIdx.x] = s[0];
}

__global__ __launch_bounds__(256) void scan_bsum(int* __restrict__ bsum, int nb) {
    __shared__ int s[256];
    const int t = threadIdx.x;
    int v = (t < nb) ? bsum[t] : 0;
    s[t] = v;
    __syncthreads();
    for (int off = 1; off < 256; off <<= 1) {
        int u = (t >= off) ? s[t - off] : 0;
        __syncthreads();
        s[t] += u;
        __syncthreads();
    }
    if (t < nb) bsum[t] = s[t] - v;
}

__global__ __launch_bounds__(256) void scan_final(const int* __restrict__ deg,
                                                  const int* __restrict__ bsum,
                                                  int* __restrict__ row_start, int n) {
    __shared__ int s[256];
    const int t = threadIdx.x;
    const int base = blockIdx.x * SCAN_B;
    int loc[4];
    int v = 0;
#pragma unroll
    for (int j = 0; j < 4; ++j) {
        int i = base + t * 4 + j;
        loc[j] = (i < n) ? deg[i] : 0;
        v += loc[j];
    }
    s[t] = v;
    __syncthreads();
    for (int off = 1; off < 256; off <<= 1) {
        int u = (t >= off) ? s[t - off] : 0;
        __syncthreads();
        s[t] += u;
        __syncthreads();
    }
    int excl = bsum[blockIdx.x] + s[t] - v;
#pragma unroll
    for (int j = 0; j < 4; ++j) {
        int i = base + t * 4 + j;
        if (i < n) row_start[i] = excl;
        excl += loc[j];
        if (i == n - 1) row_start[n] = excl;
    }
}

__global__ __launch_bounds__(256) void fill_kernel(const int* __restrict__ src,
                                                   const int* __restrict__ dst,
                                                   const int* __restrict__ row_start,
                                                   int* __restrict__ cursor,
                                                   int* __restrict__ col_idx, int E) {
    int i = blockIdx.x * 256 + threadIdx.x;
    if (i < E) {
        int d = dst[i];
        int pos = atomicAdd(&cursor[d], 1);
        col_idx[row_start[d] + pos] = src[i];
    }
}

__global__ __launch_bounds__(256) void deginv_kernel(const int* __restrict__ deg,
                                                     float* __restrict__ deg_inv, int n) {
    int i = blockIdx.x * 256 + threadIdx.x;
    if (i < n) deg_inv[i] = deg[i] > 0 ? 1.0f / (float)deg[i] : 0.0f;
}

// ---------------- W pre-conversion: fp32 row-major -> fragment-linear bf16 ----------------
// Per matrix m: group g = nt*4 + c (32 groups x 1024 B); lane slot l*16 B holds
// W[nt*16 + (l&15)][c*32 + (l>>4)*8 .. +7] as 8 bf16. grid = dim3(8, 7).

__global__ __launch_bounds__(256) void wconv_kernel(const float* __restrict__ W0,
                                                    const float* __restrict__ W1,
                                                    const float* __restrict__ W2,
                                                    const float* __restrict__ W3,
                                                    const float* __restrict__ W4,
                                                    const float* __restrict__ W5,
                                                    const float* __restrict__ W6,
                                                    ushort* __restrict__ wbuf) {
    const float* W;
    switch (blockIdx.y) {
        case 0: W = W0; break;
        case 1: W = W1; break;
        case 2: W = W2; break;
        case 3: W = W3; break;
        case 4: W = W4; break;
        case 5: W = W5; break;
        default: W = W6; break;
    }
    int idx = blockIdx.x * 256 + threadIdx.x;  // 0..2047
    int g = idx >> 6;
    int l = idx & 63;
    int nt = g >> 2, c = g & 3;
    int m15 = l & 15, kg = l >> 4;
    int r = nt * 16 + m15;
    int k0 = c * 32 + kg * 8;
    f32x4 f0 = *(const f32x4*)(W + r * DIMS + k0);
    f32x4 f1 = *(const f32x4*)(W + r * DIMS + k0 + 4);
    short8 v;
    v[0] = (short)f2bf(f0[0]); v[1] = (short)f2bf(f0[1]);
    v[2] = (short)f2bf(f0[2]); v[3] = (short)f2bf(f0[3]);
    v[4] = (short)f2bf(f1[0]); v[5] = (short)f2bf(f1[1]);
    v[6] = (short)f2bf(f1[2]); v[7] = (short)f2bf(f1[3]);
    *(short8*)(wbuf + (size_t)blockIdx.y * 16384 + g * 512 + l * 8) = v;
}

// ---------------- bf16 MFMA GEMM: Ya = X@Wa^T [, Yb = X@Wb^T] ----------------
// 256 thr / 4 waves, 64 rows/block. W pre-converted bf16, staged reg->LDS
// (fragment-linear, conflict-free ds_read_b128). A-frags global->reg. Outputs
// transposed through LDS for 16 B coalesced stores. For DUAL, wbuf must point
// at two consecutive matrices (Wa then Wb).

template <int ABF16, int DUAL>
__global__ __launch_bounds__(256) void gemm_mfma(const void* __restrict__ Xv,
                                                 const ushort* __restrict__ wbuf,
                                                 ushort* __restrict__ Ya,
                                                 ushort* __restrict__ Yb, int n) {
    __shared__ ushort wlds[(DUAL ? 2 : 1) * 16384];

    const int t = threadIdx.x;
    const int l = t & 63;
    const int w = t >> 6;
    const int kg = l >> 4;
    const int m15 = l & 15;

    // ---- stage W (already fragment-linear bf16) ----
    const int NITER = DUAL ? 16 : 8;
#pragma unroll
    for (int it = 0; it < NITER; ++it) {
        int g = it * 4 + w;
        short8 v = *(const short8*)(wbuf + (size_t)g * 512 + l * 8);
        *(short8*)((char*)wlds + g * 1024 + l * 16) = v;
    }

    // ---- A fragments: global -> reg ----
    const int row0 = blockIdx.x * 64;
    const int arow = row0 + w * 16 + m15;
    short8 af[4];
    if (arow < n) {
#pragma unroll
        for (int c = 0; c < 4; ++c) {
            if (ABF16) {
                const ushort* X = (const ushort*)Xv;
                af[c] = *(const short8*)(X + (size_t)arow * DIMS + c * 32 + kg * 8);
            } else {
                const float* X = (const float*)Xv;
                f32x4 f0 = *(const f32x4*)(X + (size_t)arow * DIMS + c * 32 + kg * 8);
                f32x4 f1 = *(const f32x4*)(X + (size_t)arow * DIMS + c * 32 + kg * 8 + 4);
                short8 v;
                v[0] = (short)f2bf(f0[0]); v[1] = (short)f2bf(f0[1]);
                v[2] = (short)f2bf(f0[2]); v[3] = (short)f2bf(f0[3]);
                v[4] = (short)f2bf(f1[0]); v[5] = (short)f2bf(f1[1]);
                v[6] = (short)f2bf(f1[2]); v[7] = (short)f2bf(f1[3]);
                af[c] = v;
            }
        }
    } else {
#pragma unroll
        for (int c = 0; c < 4; ++c) af[c] = (short8){};
    }

    __syncthreads();

    // ---- MFMA main loop ----
    f32x4 accA[8] = {};
    f32x4 accB[8] = {};
#pragma unroll
    for (int c = 0; c < 4; ++c) {
#pragma unroll
        for (int nt = 0; nt < 8; ++nt) {
            short8 bA = *(const short8*)((const char*)wlds + (nt * 4 + c) * 1024 + l * 16);
            accA[nt] = __builtin_amdgcn_mfma_f32_16x16x32_bf16(af[c], bA, accA[nt], 0, 0, 0);
            if (DUAL) {
                short8 bB = *(const short8*)((const char*)wlds + (32 + nt * 4 + c) * 1024 + l * 16);
                accB[nt] = __builtin_amdgcn_mfma_f32_16x16x32_bf16(af[c], bB, accB[nt], 0, 0, 0);
            }
        }
    }

    // ---- transpose through LDS, 16 B coalesced stores ----
    __syncthreads();  // W reads done; safe to overwrite wlds
    const int r0 = w * 16 + (l >> 4) * 4;
    ushort* outA = (ushort*)wlds;
    ushort* outB = outA + 8192;
#pragma unroll
    for (int nt = 0; nt < 8; ++nt) {
#pragma unroll
        for (int j = 0; j < 4; ++j) {
            outA[(r0 + j) * DIMS + nt * 16 + m15] = f2bf(accA[nt][j]);
            if (DUAL) outB[(r0 + j) * DIMS + nt * 16 + m15] = f2bf(accB[nt][j]);
        }
    }
    __syncthreads();
#pragma unroll
    for (int i = 0; i < 4; ++i) {
        int idx = i * 256 + t;          // 0..1023; idx*8 = row*128 + col
        int row = idx >> 4;
        int col = (idx & 15) * 8;
        if (row0 + row < n) {
            *(short8*)(Ya + (size_t)(row0 + row) * DIMS + col) = *(const short8*)(outA + idx * 8);
            if (DUAL)
                *(short8*)(Yb + (size_t)(row0 + row) * DIMS + col) = *(const short8*)(outB + idx * 8);
        }
    }
}

// ---------------- aggregation + fused epilogue (bf16 in, wide gather) ----------------
// One wave per node. 16 lanes per edge-row (16 B/lane), 4 edge-rows per step.
// h = deg_inv*sum(yl[src]) + bias + yr; mode 0: relu + identity; mode 1: L2 norm.

__global__ __launch_bounds__(256) void aggregate_kernel(
    const ushort* __restrict__ yl, const ushort* __restrict__ yr,
    const float* __restrict__ bias, const void* __restrict__ identity, int idf32,
    const int* __restrict__ row_start, const int* __restrict__ col_idx,
    const float* __restrict__ deg_inv, float* __restrict__ out_f32,
    ushort* __restrict__ out_bf16, int n, int mode) {
    const int wv = threadIdx.x >> 6;
    const int lane = threadIdx.x & 63;
    const int node = blockIdx.x * 4 + wv;
    if (node >= n) return;
    const int grp = lane >> 4;
    const int sl = lane & 15;

    const int s = row_start[node];
    const int cnt = row_start[node + 1] - s;

    float f[8] = {};
    for (int p0 = 0; p0 < cnt; p0 += 64) {
        int m = cnt - p0;
        if (m > 64) m = 64;
        int cv = (p0 + lane < cnt) ? col_idx[s + p0 + lane] : 0;
        for (int j = 0; j < m; j += 4) {
            int c = __shfl(cv, j + grp);
            if (j + grp < m) {
                short8 v = *(const short8*)(yl + (size_t)c * DIMS + sl * 8);
#pragma unroll
                for (int q = 0; q < 8; ++q) f[q] += bf2f((ushort)v[q]);
            }
        }
    }
#pragma unroll
    for (int q = 0; q < 8; ++q) {
        f[q] += __shfl_xor(f[q], 16);
        f[q] += __shfl_xor(f[q], 32);
    }

    const float di = deg_inv[node];
    f32x4 b0 = *(const f32x4*)(bias + sl * 8);
    f32x4 b1 = *(const f32x4*)(bias + sl * 8 + 4);
    short8 rv = *(const short8*)(yr + (size_t)node * DIMS + sl * 8);
    float h[8];
#pragma unroll
    for (int q = 0; q < 8; ++q)
        h[q] = fmaf(f[q], di, (q < 4 ? b0[q] : b1[q - 4])) + bf2f((ushort)rv[q]);

    if (mode == 0) {
        if (idf32) {
            const float* idp = (const float*)identity + (size_t)node * DIMS + sl * 8;
            f32x4 i0 = *(const f32x4*)idp;
            f32x4 i1 = *(const f32x4*)(idp + 4);
#pragma unroll
            for (int q = 0; q < 8; ++q)
                h[q] = fmaxf(h[q], 0.f) + (q < 4 ? i0[q] : i1[q - 4]);
        } else {
            short8 iv = *(const short8*)((const ushort*)identity + (size_t)node * DIMS + sl * 8);
#pragma unroll
            for (int q = 0; q < 8; ++q) h[q] = fmaxf(h[q], 0.f) + bf2f((ushort)iv[q]);
        }
    } else {
        float ss = 0.f;
#pragma unroll
        for (int q = 0; q < 8; ++q) ss += h[q] * h[q];
        ss += __shfl_xor(ss, 1);
        ss += __shfl_xor(ss, 2);
        ss += __shfl_xor(ss, 4);
        ss += __shfl_xor(ss, 8);
        float inv = 1.0f / fmaxf(sqrtf(ss), 1e-12f);
#pragma unroll
        for (int q = 0; q < 8; ++q) h[q] *= inv;
    }

    if (grp == 0) {
        if (out_bf16) {
            short8 o;
#pragma unroll
            for (int q = 0; q < 8; ++q) o[q] = (short)f2bf(h[q]);
            *(short8*)(out_bf16 + (size_t)node * DIMS + sl * 8) = o;
        }
        if (out_f32) {
            f32x4 o0, o1;
#pragma unroll
            for (int q = 0; q < 4; ++q) { o0[q] = h[q]; o1[q] = h[q + 4]; }
            *(f32x4*)(out_f32 + (size_t)node * DIMS + sl * 8) = o0;
            *(f32x4*)(out_f32 + (size_t)node * DIMS + sl * 8 + 4) = o1;
        }
    }
}

// ---------------- launch ----------------

extern "C" void kernel_launch(void* const* d_in, const int* in_sizes, int n_in,
                              void* d_out, int out_size, void* d_ws, size_t ws_size,
                              hipStream_t stream) {
    const float* x     = (const float*)d_in[0];
    const int*   eidx  = (const int*)d_in[1];
    const float* Wproj = (const float*)d_in[2];
    const float* W1_l  = (const float*)d_in[3];
    const float* b1    = (const float*)d_in[4];
    const float* W1_r  = (const float*)d_in[5];
    const float* W2_l  = (const float*)d_in[6];
    const float* b2    = (const float*)d_in[7];
    const float* W2_r  = (const float*)d_in[8];
    const float* W3_l  = (const float*)d_in[9];
    const float* b3    = (const float*)d_in[10];
    const float* W3_r  = (const float*)d_in[11];
    float* out = (float*)d_out;

    const int N = in_sizes[0] / DIMS;
    const int E = in_sizes[1] / 2;
    const int* src = eidx;
    const int* dst = eidx + E;

    size_t off = 0;
    auto alloc = [&](size_t bytes) {
        void* p = (char*)d_ws + off;
        off += (bytes + 511) & ~(size_t)511;
        return p;
    };
    int*    deg_cnt   = (int*)alloc((size_t)N * 4);
    int*    cursor    = (int*)alloc((size_t)N * 4);
    int*    row_start = (int*)alloc((size_t)(N + 1) * 4);
    float*  deg_inv   = (float*)alloc((size_t)N * 4);
    int*    col_idx   = (int*)alloc((size_t)E * 4);
    int*    bsum      = (int*)alloc((size_t)1024 * 4);
    ushort* wbuf      = (ushort*)alloc((size_t)7 * 16384 * 2);
    ushort* h0b       = (ushort*)alloc((size_t)N * DIMS * 2);  // reused as h2b
    ushort* h1b       = (ushort*)alloc((size_t)N * DIMS * 2);
    ushort* ylb       = (ushort*)alloc((size_t)N * DIMS * 2);
    ushort* yrb       = (ushort*)alloc((size_t)N * DIMS * 2);
    ushort* h2b       = h0b;
    (void)ws_size;

    hipMemsetAsync(deg_cnt, 0, (size_t)N * 4, stream);
    hipMemsetAsync(cursor, 0, (size_t)N * 4, stream);

    const int egrid = (E + 255) / 256;
    const int ngrid = (N + 255) / 256;
    const int sgrid = (N + SCAN_B - 1) / SCAN_B;
    const int ggrid = (N + 63) / 64;
    const int agrid = (N + 3) / 4;

    hist_kernel<<<egrid, 256, 0, stream>>>(dst, deg_cnt, E);
    scan_reduce<<<sgrid, 256, 0, stream>>>(deg_cnt, bsum, N);
    scan_bsum<<<1, 256, 0, stream>>>(bsum, sgrid);
    scan_final<<<sgrid, 256, 0, stream>>>(deg_cnt, bsum, row_start, N);
    fill_kernel<<<egrid, 256, 0, stream>>>(src, dst, row_start, cursor, col_idx, E);
    deginv_kernel<<<ngrid, 256, 0, stream>>>(deg_cnt, deg_inv, N);
    wconv_kernel<<<dim3(8, 7), 256, 0, stream>>>(Wproj, W1_l, W1_r, W2_l, W2_r, W3_l, W3_r,
                                                 wbuf);

    // h0 = x @ Wproj^T (fp32 A, single output)
    gemm_mfma<0, 0><<<ggrid, 256, 0, stream>>>(x, wbuf, h0b, nullptr, N);

    // layer 1 (identity = x fp32; h1 kept bf16 only)
    gemm_mfma<1, 1><<<ggrid, 256, 0, stream>>>(h0b, wbuf + 1 * 16384, ylb, yrb, N);
    aggregate_kernel<<<agrid, 256, 0, stream>>>(ylb, yrb, b1, x, 1, row_start, col_idx,
                                                deg_inv, nullptr, h1b, N, 0);

    // layer 2 (identity = h1b bf16)
    gemm_mfma<1, 1><<<ggrid, 256, 0, stream>>>(h1b, wbuf + 3 * 16384, ylb, yrb, N);
    aggregate_kernel<<<agrid, 256, 0, stream>>>(ylb, yrb, b2, h1b, 0, row_start, col_idx,
                                                deg_inv, nullptr, h2b, N, 0);

    // layer 3 (L2 normalize -> d_out fp32)
    gemm_mfma<1, 1><<<ggrid, 256, 0, stream>>>(h2b, wbuf + 5 * 16384, ylb, yrb, N);
    aggregate_kernel<<<agrid, 256, 0, stream>>>(ylb, yrb, b3, nullptr, 0, row_start, col_idx,
                                                deg_inv, out, nullptr, N, 1);
}

// Round 6
// 417.667 us; speedup vs baseline: 3.2535x; 1.0465x over previous
//
#include <hip/hip_runtime.h>

typedef unsigned int uint;
typedef unsigned short ushort;
typedef float f32x4 __attribute__((ext_vector_type(4)));
typedef short short8 __attribute__((ext_vector_type(8)));

#define DIMS 128
#define SCAN_B 1024

__device__ __forceinline__ ushort f2bf(float f) {
    uint u = __builtin_bit_cast(uint, f);
    u += 0x7fffu + ((u >> 16) & 1u);  // RNE
    return (ushort)(u >> 16);
}
__device__ __forceinline__ float bf2f(ushort h) {
    uint u = (uint)h << 16;
    return __builtin_bit_cast(float, u);
}

// ---------------- CSR build ----------------

__global__ __launch_bounds__(256) void hist_kernel(const int* __restrict__ dst,
                                                   int* __restrict__ deg, int E) {
    int i = blockIdx.x * 256 + threadIdx.x;
    if (i < E) atomicAdd(&deg[dst[i]], 1);
}

__global__ __launch_bounds__(256) void scan_reduce(const int* __restrict__ deg,
                                                   int* __restrict__ bsum, int n) {
    __shared__ int s[256];
    const int t = threadIdx.x;
    const int base = blockIdx.x * SCAN_B;
    int v = 0;
#pragma unroll
    for (int j = 0; j < 4; ++j) {
        int i = base + t * 4 + j;
        if (i < n) v += deg[i];
    }
    s[t] = v;
    __syncthreads();
    for (int off = 128; off > 0; off >>= 1) {
        if (t < off) s[t] += s[t + off];
        __syncthreads();
    }
    if (t == 0) bsum[blockIdx.x] = s[0];
}

__global__ __launch_bounds__(256) void scan_bsum(int* __restrict__ bsum, int nb) {
    __shared__ int s[256];
    const int t = threadIdx.x;
    int v = (t < nb) ? bsum[t] : 0;
    s[t] = v;
    __syncthreads();
    for (int off = 1; off < 256; off <<= 1) {
        int u = (t >= off) ? s[t - off] : 0;
        __syncthreads();
        s[t] += u;
        __syncthreads();
    }
    if (t < nb) bsum[t] = s[t] - v;
}

// stage 3: per-block exclusive scan + block offset -> row_start; also emits deg_inv.
__global__ __launch_bounds__(256) void scan_final(const int* __restrict__ deg,
                                                  const int* __restrict__ bsum,
                                                  int* __restrict__ row_start,
                                                  float* __restrict__ deg_inv, int n) {
    __shared__ int s[256];
    const int t = threadIdx.x;
    const int base = blockIdx.x * SCAN_B;
    int loc[4];
    int v = 0;
#pragma unroll
    for (int j = 0; j < 4; ++j) {
        int i = base + t * 4 + j;
        loc[j] = (i < n) ? deg[i] : 0;
        v += loc[j];
    }
    s[t] = v;
    __syncthreads();
    for (int off = 1; off < 256; off <<= 1) {
        int u = (t >= off) ? s[t - off] : 0;
        __syncthreads();
        s[t] += u;
        __syncthreads();
    }
    int excl = bsum[blockIdx.x] + s[t] - v;
#pragma unroll
    for (int j = 0; j < 4; ++j) {
        int i = base + t * 4 + j;
        if (i < n) {
            row_start[i] = excl;
            deg_inv[i] = loc[j] > 0 ? 1.0f / (float)loc[j] : 0.0f;
        }
        excl += loc[j];
        if (i == n - 1) row_start[n] = excl;
    }
}

__global__ __launch_bounds__(256) void fill_kernel(const int* __restrict__ src,
                                                   const int* __restrict__ dst,
                                                   const int* __restrict__ row_start,
                                                   int* __restrict__ cursor,
                                                   int* __restrict__ col_idx, int E) {
    int i = blockIdx.x * 256 + threadIdx.x;
    if (i < E) {
        int d = dst[i];
        int pos = atomicAdd(&cursor[d], 1);
        col_idx[row_start[d] + pos] = src[i];
    }
}

// ---------------- W pre-conversion: fp32 row-major -> fragment-linear bf16 ----------------

__global__ __launch_bounds__(256) void wconv_kernel(const float* __restrict__ W0,
                                                    const float* __restrict__ W1,
                                                    const float* __restrict__ W2,
                                                    const float* __restrict__ W3,
                                                    const float* __restrict__ W4,
                                                    const float* __restrict__ W5,
                                                    const float* __restrict__ W6,
                                                    ushort* __restrict__ wbuf) {
    const float* W;
    switch (blockIdx.y) {
        case 0: W = W0; break;
        case 1: W = W1; break;
        case 2: W = W2; break;
        case 3: W = W3; break;
        case 4: W = W4; break;
        case 5: W = W5; break;
        default: W = W6; break;
    }
    int idx = blockIdx.x * 256 + threadIdx.x;  // 0..2047
    int g = idx >> 6;
    int l = idx & 63;
    int nt = g >> 2, c = g & 3;
    int m15 = l & 15, kg = l >> 4;
    int r = nt * 16 + m15;
    int k0 = c * 32 + kg * 8;
    f32x4 f0 = *(const f32x4*)(W + r * DIMS + k0);
    f32x4 f1 = *(const f32x4*)(W + r * DIMS + k0 + 4);
    short8 v;
    v[0] = (short)f2bf(f0[0]); v[1] = (short)f2bf(f0[1]);
    v[2] = (short)f2bf(f0[2]); v[3] = (short)f2bf(f0[3]);
    v[4] = (short)f2bf(f1[0]); v[5] = (short)f2bf(f1[1]);
    v[6] = (short)f2bf(f1[2]); v[7] = (short)f2bf(f1[3]);
    *(short8*)(wbuf + (size_t)blockIdx.y * 16384 + g * 512 + l * 8) = v;
}

// ---------------- bf16 MFMA GEMM: Ya = X@Wa^T [, Yb = X@Wb^T] ----------------
// 512 thr / 8 waves, 128 rows/block (wave w owns rows w*16..w*16+15). W
// pre-converted bf16 staged reg->LDS fragment-linear (conflict-free
// ds_read_b128, all-wave broadcast). Outputs transposed through LDS (reusing
// the W buffer) for 16 B coalesced stores.

template <int ABF16, int DUAL>
__global__ __launch_bounds__(512) void gemm_mfma(const void* __restrict__ Xv,
                                                 const ushort* __restrict__ wbuf,
                                                 ushort* __restrict__ Ya,
                                                 ushort* __restrict__ Yb, int n) {
    __shared__ ushort wlds[(DUAL ? 2 : 1) * 16384];

    const int t = threadIdx.x;
    const int l = t & 63;
    const int w = t >> 6;   // 0..7
    const int kg = l >> 4;
    const int m15 = l & 15;

    // ---- stage W ----
    const int NITER = DUAL ? 8 : 4;  // 64 / 32 groups over 8 waves
#pragma unroll
    for (int it = 0; it < NITER; ++it) {
        int g = it * 8 + w;
        short8 v = *(const short8*)(wbuf + (size_t)g * 512 + l * 8);
        *(short8*)((char*)wlds + g * 1024 + l * 16) = v;
    }

    // ---- A fragments: global -> reg ----
    const int row0 = blockIdx.x * 128;
    const int arow = row0 + w * 16 + m15;
    short8 af[4];
    if (arow < n) {
#pragma unroll
        for (int c = 0; c < 4; ++c) {
            if (ABF16) {
                const ushort* X = (const ushort*)Xv;
                af[c] = *(const short8*)(X + (size_t)arow * DIMS + c * 32 + kg * 8);
            } else {
                const float* X = (const float*)Xv;
                f32x4 f0 = *(const f32x4*)(X + (size_t)arow * DIMS + c * 32 + kg * 8);
                f32x4 f1 = *(const f32x4*)(X + (size_t)arow * DIMS + c * 32 + kg * 8 + 4);
                short8 v;
                v[0] = (short)f2bf(f0[0]); v[1] = (short)f2bf(f0[1]);
                v[2] = (short)f2bf(f0[2]); v[3] = (short)f2bf(f0[3]);
                v[4] = (short)f2bf(f1[0]); v[5] = (short)f2bf(f1[1]);
                v[6] = (short)f2bf(f1[2]); v[7] = (short)f2bf(f1[3]);
                af[c] = v;
            }
        }
    } else {
#pragma unroll
        for (int c = 0; c < 4; ++c) af[c] = (short8){};
    }

    __syncthreads();

    // ---- MFMA main loop ----
    f32x4 accA[8] = {};
    f32x4 accB[8] = {};
#pragma unroll
    for (int c = 0; c < 4; ++c) {
#pragma unroll
        for (int nt = 0; nt < 8; ++nt) {
            short8 bA = *(const short8*)((const char*)wlds + (nt * 4 + c) * 1024 + l * 16);
            accA[nt] = __builtin_amdgcn_mfma_f32_16x16x32_bf16(af[c], bA, accA[nt], 0, 0, 0);
            if (DUAL) {
                short8 bB = *(const short8*)((const char*)wlds + (32 + nt * 4 + c) * 1024 + l * 16);
                accB[nt] = __builtin_amdgcn_mfma_f32_16x16x32_bf16(af[c], bB, accB[nt], 0, 0, 0);
            }
        }
    }

    // ---- transpose through LDS (reuse wlds), 16 B coalesced stores ----
    __syncthreads();
    const int r0 = w * 16 + (l >> 4) * 4;
    ushort* outA = (ushort*)wlds;          // 128x128 bf16 = 32 KiB
    ushort* outB = outA + 16384;
#pragma unroll
    for (int nt = 0; nt < 8; ++nt) {
#pragma unroll
        for (int j = 0; j < 4; ++j) {
            outA[(r0 + j) * DIMS + nt * 16 + m15] = f2bf(accA[nt][j]);
            if (DUAL) outB[(r0 + j) * DIMS + nt * 16 + m15] = f2bf(accB[nt][j]);
        }
    }
    __syncthreads();
#pragma unroll
    for (int i = 0; i < 4; ++i) {
        int idx = i * 512 + t;             // 0..2047; row = idx>>4, col=(idx&15)*8
        int row = idx >> 4;
        int col = (idx & 15) * 8;
        if (row0 + row < n) {
            *(short8*)(Ya + (size_t)(row0 + row) * DIMS + col) = *(const short8*)(outA + idx * 8);
            if (DUAL)
                *(short8*)(Yb + (size_t)(row0 + row) * DIMS + col) = *(const short8*)(outB + idx * 8);
        }
    }
}

// ---------------- aggregation + fused epilogue (bf16 in, wide gather) ----------------

__global__ __launch_bounds__(256) void aggregate_kernel(
    const ushort* __restrict__ yl, const ushort* __restrict__ yr,
    const float* __restrict__ bias, const void* __restrict__ identity, int idf32,
    const int* __restrict__ row_start, const int* __restrict__ col_idx,
    const float* __restrict__ deg_inv, float* __restrict__ out_f32,
    ushort* __restrict__ out_bf16, int n, int mode) {
    const int wv = threadIdx.x >> 6;
    const int lane = threadIdx.x & 63;
    const int node = blockIdx.x * 4 + wv;
    if (node >= n) return;
    const int grp = lane >> 4;
    const int sl = lane & 15;

    const int s = row_start[node];
    const int cnt = row_start[node + 1] - s;

    float f[8] = {};
    for (int p0 = 0; p0 < cnt; p0 += 64) {
        int m = cnt - p0;
        if (m > 64) m = 64;
        int cv = (p0 + lane < cnt) ? col_idx[s + p0 + lane] : 0;
        for (int j = 0; j < m; j += 4) {
            int c = __shfl(cv, j + grp);
            if (j + grp < m) {
                short8 v = *(const short8*)(yl + (size_t)c * DIMS + sl * 8);
#pragma unroll
                for (int q = 0; q < 8; ++q) f[q] += bf2f((ushort)v[q]);
            }
        }
    }
#pragma unroll
    for (int q = 0; q < 8; ++q) {
        f[q] += __shfl_xor(f[q], 16);
        f[q] += __shfl_xor(f[q], 32);
    }

    const float di = deg_inv[node];
    f32x4 b0 = *(const f32x4*)(bias + sl * 8);
    f32x4 b1 = *(const f32x4*)(bias + sl * 8 + 4);
    short8 rv = *(const short8*)(yr + (size_t)node * DIMS + sl * 8);
    float h[8];
#pragma unroll
    for (int q = 0; q < 8; ++q)
        h[q] = fmaf(f[q], di, (q < 4 ? b0[q] : b1[q - 4])) + bf2f((ushort)rv[q]);

    if (mode == 0) {
        if (idf32) {
            const float* idp = (const float*)identity + (size_t)node * DIMS + sl * 8;
            f32x4 i0 = *(const f32x4*)idp;
            f32x4 i1 = *(const f32x4*)(idp + 4);
#pragma unroll
            for (int q = 0; q < 8; ++q)
                h[q] = fmaxf(h[q], 0.f) + (q < 4 ? i0[q] : i1[q - 4]);
        } else {
            short8 iv = *(const short8*)((const ushort*)identity + (size_t)node * DIMS + sl * 8);
#pragma unroll
            for (int q = 0; q < 8; ++q) h[q] = fmaxf(h[q], 0.f) + bf2f((ushort)iv[q]);
        }
    } else {
        float ss = 0.f;
#pragma unroll
        for (int q = 0; q < 8; ++q) ss += h[q] * h[q];
        ss += __shfl_xor(ss, 1);
        ss += __shfl_xor(ss, 2);
        ss += __shfl_xor(ss, 4);
        ss += __shfl_xor(ss, 8);
        float inv = 1.0f / fmaxf(sqrtf(ss), 1e-12f);
#pragma unroll
        for (int q = 0; q < 8; ++q) h[q] *= inv;
    }

    if (grp == 0) {
        if (out_bf16) {
            short8 o;
#pragma unroll
            for (int q = 0; q < 8; ++q) o[q] = (short)f2bf(h[q]);
            *(short8*)(out_bf16 + (size_t)node * DIMS + sl * 8) = o;
        }
        if (out_f32) {
            f32x4 o0, o1;
#pragma unroll
            for (int q = 0; q < 4; ++q) { o0[q] = h[q]; o1[q] = h[q + 4]; }
            *(f32x4*)(out_f32 + (size_t)node * DIMS + sl * 8) = o0;
            *(f32x4*)(out_f32 + (size_t)node * DIMS + sl * 8 + 4) = o1;
        }
    }
}

// ---------------- launch ----------------

extern "C" void kernel_launch(void* const* d_in, const int* in_sizes, int n_in,
                              void* d_out, int out_size, void* d_ws, size_t ws_size,
                              hipStream_t stream) {
    const float* x     = (const float*)d_in[0];
    const int*   eidx  = (const int*)d_in[1];
    const float* Wproj = (const float*)d_in[2];
    const float* W1_l  = (const float*)d_in[3];
    const float* b1    = (const float*)d_in[4];
    const float* W1_r  = (const float*)d_in[5];
    const float* W2_l  = (const float*)d_in[6];
    const float* b2    = (const float*)d_in[7];
    const float* W2_r  = (const float*)d_in[8];
    const float* W3_l  = (const float*)d_in[9];
    const float* b3    = (const float*)d_in[10];
    const float* W3_r  = (const float*)d_in[11];
    float* out = (float*)d_out;

    const int N = in_sizes[0] / DIMS;
    const int E = in_sizes[1] / 2;
    const int* src = eidx;
    const int* dst = eidx + E;

    size_t off = 0;
    auto alloc = [&](size_t bytes) {
        void* p = (char*)d_ws + off;
        off += (bytes + 511) & ~(size_t)511;
        return p;
    };
    int*    deg_cnt   = (int*)alloc((size_t)N * 4);
    int*    cursor    = (int*)alloc((size_t)N * 4);
    int*    row_start = (int*)alloc((size_t)(N + 1) * 4);
    float*  deg_inv   = (float*)alloc((size_t)N * 4);
    int*    col_idx   = (int*)alloc((size_t)E * 4);
    int*    bsum      = (int*)alloc((size_t)1024 * 4);
    ushort* wbuf      = (ushort*)alloc((size_t)7 * 16384 * 2);
    ushort* h0b       = (ushort*)alloc((size_t)N * DIMS * 2);  // reused as h2b
    ushort* h1b       = (ushort*)alloc((size_t)N * DIMS * 2);
    ushort* ylb       = (ushort*)alloc((size_t)N * DIMS * 2);
    ushort* yrb       = (ushort*)alloc((size_t)N * DIMS * 2);
    ushort* h2b       = h0b;
    (void)ws_size;

    hipMemsetAsync(deg_cnt, 0, (size_t)N * 4, stream);
    hipMemsetAsync(cursor, 0, (size_t)N * 4, stream);

    const int egrid = (E + 255) / 256;
    const int sgrid = (N + SCAN_B - 1) / SCAN_B;
    const int ggrid = (N + 127) / 128;
    const int agrid = (N + 3) / 4;

    hist_kernel<<<egrid, 256, 0, stream>>>(dst, deg_cnt, E);
    scan_reduce<<<sgrid, 256, 0, stream>>>(deg_cnt, bsum, N);
    scan_bsum<<<1, 256, 0, stream>>>(bsum, sgrid);
    scan_final<<<sgrid, 256, 0, stream>>>(deg_cnt, bsum, row_start, deg_inv, N);
    fill_kernel<<<egrid, 256, 0, stream>>>(src, dst, row_start, cursor, col_idx, E);
    wconv_kernel<<<dim3(8, 7), 256, 0, stream>>>(Wproj, W1_l, W1_r, W2_l, W2_r, W3_l, W3_r,
                                                 wbuf);

    // h0 = x @ Wproj^T (fp32 A, single output)
    gemm_mfma<0, 0><<<ggrid, 512, 0, stream>>>(x, wbuf, h0b, nullptr, N);

    // layer 1 (identity = x fp32; h1 kept bf16 only)
    gemm_mfma<1, 1><<<ggrid, 512, 0, stream>>>(h0b, wbuf + 1 * 16384, ylb, yrb, N);
    aggregate_kernel<<<agrid, 256, 0, stream>>>(ylb, yrb, b1, x, 1, row_start, col_idx,
                                                deg_inv, nullptr, h1b, N, 0);

    // layer 2 (identity = h1b bf16)
    gemm_mfma<1, 1><<<ggrid, 512, 0, stream>>>(h1b, wbuf + 3 * 16384, ylb, yrb, N);
    aggregate_kernel<<<agrid, 256, 0, stream>>>(ylb, yrb, b2, h1b, 0, row_start, col_idx,
                                                deg_inv, nullptr, h2b, N, 0);

    // layer 3 (L2 normalize -> d_out fp32)
    gemm_mfma<1, 1><<<ggrid, 512, 0, stream>>>(h2b, wbuf + 5 * 16384, ylb, yrb, N);
    aggregate_kernel<<<agrid, 256, 0, stream>>>(ylb, yrb, b3, nullptr, 0, row_start, col_idx,
                                                deg_inv, out, nullptr, N, 1);
}

// Round 7
// 407.281 us; speedup vs baseline: 3.3365x; 1.0255x over previous
//
#include <hip/hip_runtime.h>

typedef unsigned int uint;
typedef unsigned short ushort;
typedef float f32x4 __attribute__((ext_vector_type(4)));
typedef short short8 __attribute__((ext_vector_type(8)));

#define DIMS 128
#define SCAN_B 1024

__device__ __forceinline__ ushort f2bf(float f) {
    uint u = __builtin_bit_cast(uint, f);
    u += 0x7fffu + ((u >> 16) & 1u);  // RNE
    return (ushort)(u >> 16);
}
__device__ __forceinline__ float bf2f(ushort h) {
    uint u = (uint)h << 16;
    return __builtin_bit_cast(float, u);
}

// ---------------- CSR build ----------------

__global__ __launch_bounds__(256) void hist_kernel(const int* __restrict__ dst,
                                                   int* __restrict__ deg, int E) {
    int i = blockIdx.x * 256 + threadIdx.x;
    if (i < E) atomicAdd(&deg[dst[i]], 1);
}

__global__ __launch_bounds__(256) void scan_reduce(const int* __restrict__ deg,
                                                   int* __restrict__ bsum, int n) {
    __shared__ int s[256];
    const int t = threadIdx.x;
    const int base = blockIdx.x * SCAN_B;
    int v = 0;
#pragma unroll
    for (int j = 0; j < 4; ++j) {
        int i = base + t * 4 + j;
        if (i < n) v += deg[i];
    }
    s[t] = v;
    __syncthreads();
    for (int off = 128; off > 0; off >>= 1) {
        if (t < off) s[t] += s[t + off];
        __syncthreads();
    }
    if (t == 0) bsum[blockIdx.x] = s[0];
}

__global__ __launch_bounds__(256) void scan_bsum(int* __restrict__ bsum, int nb) {
    __shared__ int s[256];
    const int t = threadIdx.x;
    int v = (t < nb) ? bsum[t] : 0;
    s[t] = v;
    __syncthreads();
    for (int off = 1; off < 256; off <<= 1) {
        int u = (t >= off) ? s[t - off] : 0;
        __syncthreads();
        s[t] += u;
        __syncthreads();
    }
    if (t < nb) bsum[t] = s[t] - v;
}

__global__ __launch_bounds__(256) void scan_final(const int* __restrict__ deg,
                                                  const int* __restrict__ bsum,
                                                  int* __restrict__ row_start,
                                                  float* __restrict__ deg_inv, int n) {
    __shared__ int s[256];
    const int t = threadIdx.x;
    const int base = blockIdx.x * SCAN_B;
    int loc[4];
    int v = 0;
#pragma unroll
    for (int j = 0; j < 4; ++j) {
        int i = base + t * 4 + j;
        loc[j] = (i < n) ? deg[i] : 0;
        v += loc[j];
    }
    s[t] = v;
    __syncthreads();
    for (int off = 1; off < 256; off <<= 1) {
        int u = (t >= off) ? s[t - off] : 0;
        __syncthreads();
        s[t] += u;
        __syncthreads();
    }
    int excl = bsum[blockIdx.x] + s[t] - v;
#pragma unroll
    for (int j = 0; j < 4; ++j) {
        int i = base + t * 4 + j;
        if (i < n) {
            row_start[i] = excl;
            deg_inv[i] = loc[j] > 0 ? 1.0f / (float)loc[j] : 0.0f;
        }
        excl += loc[j];
        if (i == n - 1) row_start[n] = excl;
    }
}

__global__ __launch_bounds__(256) void fill_kernel(const int* __restrict__ src,
                                                   const int* __restrict__ dst,
                                                   const int* __restrict__ row_start,
                                                   int* __restrict__ cursor,
                                                   int* __restrict__ col_idx, int E) {
    int i = blockIdx.x * 256 + threadIdx.x;
    if (i < E) {
        int d = dst[i];
        int pos = atomicAdd(&cursor[d], 1);
        col_idx[row_start[d] + pos] = src[i];
    }
}

// ---------------- W pre-conversion -> fragment-linear bf16 ----------------
// Slot 0: Wproj (K=128, 32 groups, g=nt*4+c). Slots 1..3: fused [W_l|W_r]
// (K=256, 64 groups, g=nt*8+c; k=c*32+kg*8; k<128 -> W_l, else W_r).

__global__ __launch_bounds__(256) void wconv_kernel(const float* __restrict__ Wp,
                                                    const float* __restrict__ W1l,
                                                    const float* __restrict__ W1r,
                                                    const float* __restrict__ W2l,
                                                    const float* __restrict__ W2r,
                                                    const float* __restrict__ W3l,
                                                    const float* __restrict__ W3r,
                                                    ushort* __restrict__ wbuf) {
    const int y = blockIdx.y;
    int idx = blockIdx.x * 256 + threadIdx.x;
    int l = idx & 63;
    int m15 = l & 15, kg = l >> 4;
    if (y == 0) {
        if (idx >= 2048) return;
        int g = idx >> 6;  // 0..31
        int nt = g >> 2, c = g & 3;
        int r = nt * 16 + m15;
        int k0 = c * 32 + kg * 8;
        f32x4 f0 = *(const f32x4*)(Wp + r * DIMS + k0);
        f32x4 f1 = *(const f32x4*)(Wp + r * DIMS + k0 + 4);
        short8 v;
        v[0] = (short)f2bf(f0[0]); v[1] = (short)f2bf(f0[1]);
        v[2] = (short)f2bf(f0[2]); v[3] = (short)f2bf(f0[3]);
        v[4] = (short)f2bf(f1[0]); v[5] = (short)f2bf(f1[1]);
        v[6] = (short)f2bf(f1[2]); v[7] = (short)f2bf(f1[3]);
        *(short8*)(wbuf + (size_t)g * 512 + l * 8) = v;
    } else {
        const float* Wl = (y == 1) ? W1l : (y == 2) ? W2l : W3l;
        const float* Wr = (y == 1) ? W1r : (y == 2) ? W2r : W3r;
        int g = idx >> 6;  // 0..63
        int nt = g >> 3, c = g & 7;
        int r = nt * 16 + m15;
        int k = c * 32 + kg * 8;
        const float* W = (k < 128) ? Wl : Wr;
        int kk = k & 127;
        f32x4 f0 = *(const f32x4*)(W + r * DIMS + kk);
        f32x4 f1 = *(const f32x4*)(W + r * DIMS + kk + 4);
        short8 v;
        v[0] = (short)f2bf(f0[0]); v[1] = (short)f2bf(f0[1]);
        v[2] = (short)f2bf(f0[2]); v[3] = (short)f2bf(f0[3]);
        v[4] = (short)f2bf(f1[0]); v[5] = (short)f2bf(f1[1]);
        v[6] = (short)f2bf(f1[2]); v[7] = (short)f2bf(f1[3]);
        *(short8*)(wbuf + 16384 + (size_t)(y - 1) * 32768 + (size_t)g * 512 + l * 8) = v;
    }
}

// ---------------- fused GEMM ----------------
// MODE 0: Ya = bf16(x fp32 @ Wproj^T), Yb = bf16(x) passthrough. K=128.
// MODE 1: Ya = bf16(relu([Xm|Xh]@W'^T + bias) + idb). K=256.
// MODE 2: outf = L2norm_row([Xm|Xh]@W'^T + bias), fp32. K=256.
// 512 thr / 8 waves, 128 rows/block. fp32 epilogue staged via LDS (MODE1/2).

template <int MODE>
__global__ __launch_bounds__(512) void gemm_fused(const void* __restrict__ Xa,
                                                  const ushort* __restrict__ Xh,
                                                  const ushort* __restrict__ wbuf,
                                                  const float* __restrict__ bias,
                                                  const ushort* __restrict__ idb,
                                                  ushort* __restrict__ Ya,
                                                  ushort* __restrict__ Yb,
                                                  float* __restrict__ outf, int n) {
    constexpr int NC = (MODE == 0) ? 4 : 8;
    __shared__ ushort wlds[32768];  // 64 KiB

    const int t = threadIdx.x;
    const int l = t & 63;
    const int w = t >> 6;
    const int kg = l >> 4;
    const int m15 = l & 15;

    // ---- stage W (fragment-linear bf16, NC*8 groups over 8 waves) ----
#pragma unroll
    for (int it = 0; it < NC; ++it) {
        int g = it * 8 + w;
        short8 v = *(const short8*)(wbuf + (size_t)g * 512 + l * 8);
        *(short8*)((char*)wlds + g * 1024 + l * 16) = v;
    }

    // ---- A fragments ----
    const int row0 = blockIdx.x * 128;
    const int arow = row0 + w * 16 + m15;
    short8 af[NC];
    if (arow < n) {
        if (MODE == 0) {
            const float* X = (const float*)Xa;
#pragma unroll
            for (int c = 0; c < 4; ++c) {
                f32x4 f0 = *(const f32x4*)(X + (size_t)arow * DIMS + c * 32 + kg * 8);
                f32x4 f1 = *(const f32x4*)(X + (size_t)arow * DIMS + c * 32 + kg * 8 + 4);
                short8 v;
                v[0] = (short)f2bf(f0[0]); v[1] = (short)f2bf(f0[1]);
                v[2] = (short)f2bf(f0[2]); v[3] = (short)f2bf(f0[3]);
                v[4] = (short)f2bf(f1[0]); v[5] = (short)f2bf(f1[1]);
                v[6] = (short)f2bf(f1[2]); v[7] = (short)f2bf(f1[3]);
                af[c] = v;
            }
        } else {
            const ushort* Xm = (const ushort*)Xa;
#pragma unroll
            for (int c = 0; c < 4; ++c)
                af[c] = *(const short8*)(Xm + (size_t)arow * DIMS + c * 32 + kg * 8);
#pragma unroll
            for (int c = 0; c < 4; ++c)
                af[4 + c] = *(const short8*)(Xh + (size_t)arow * DIMS + c * 32 + kg * 8);
        }
    } else {
#pragma unroll
        for (int c = 0; c < NC; ++c) af[c] = (short8){};
    }

    __syncthreads();

    // ---- MFMA ----
    f32x4 acc[8] = {};
#pragma unroll
    for (int c = 0; c < NC; ++c)
#pragma unroll
        for (int nt = 0; nt < 8; ++nt) {
            short8 b = *(const short8*)((const char*)wlds + (nt * NC + c) * 1024 + l * 16);
            acc[nt] = __builtin_amdgcn_mfma_f32_16x16x32_bf16(af[c], b, acc[nt], 0, 0, 0);
        }

    // ---- epilogue ----
    __syncthreads();
    const int r0 = w * 16 + (l >> 4) * 4;

    if (MODE == 0) {
        ushort* outA = wlds;            // [128][128] bf16
        ushort* outB = wlds + 16384;
#pragma unroll
        for (int nt = 0; nt < 8; ++nt)
#pragma unroll
            for (int j = 0; j < 4; ++j)
                outA[(r0 + j) * DIMS + nt * 16 + m15] = f2bf(acc[nt][j]);
        const int rl = w * 16 + m15;
#pragma unroll
        for (int c = 0; c < 4; ++c)
            *(short8*)(outB + rl * DIMS + c * 32 + kg * 8) = af[c];
        __syncthreads();
#pragma unroll
        for (int i = 0; i < 4; ++i) {
            int idx = i * 512 + t;
            int row = idx >> 4, col = (idx & 15) * 8;
            if (row0 + row < n) {
                *(short8*)(Ya + (size_t)(row0 + row) * DIMS + col) = *(const short8*)(outA + idx * 8);
                *(short8*)(Yb + (size_t)(row0 + row) * DIMS + col) = *(const short8*)(outB + idx * 8);
            }
        }
    } else {
        float* outF = (float*)wlds;     // [128][128] f32, 4-float-block XOR swizzle
#pragma unroll
        for (int nt = 0; nt < 8; ++nt)
#pragma unroll
            for (int j = 0; j < 4; ++j) {
                int row = r0 + j;
                int col = nt * 16 + m15;
                int sc = (((col >> 2) ^ (row & 7)) << 2) | (col & 3);
                outF[row * DIMS + sc] = acc[nt][j];
            }
        __syncthreads();
#pragma unroll
        for (int i = 0; i < 4; ++i) {
            int idx = i * 512 + t;
            int row = idx >> 4, col = (idx & 15) * 8;
            if (row0 + row < n) {
                int x7 = row & 7;
                int cb = col >> 2;
                f32x4 o0 = *(const f32x4*)(outF + row * DIMS + ((cb ^ x7) << 2));
                f32x4 o1 = *(const f32x4*)(outF + row * DIMS + (((cb + 1) ^ x7) << 2));
                f32x4 b0 = *(const f32x4*)(bias + col);
                f32x4 b1 = *(const f32x4*)(bias + col + 4);
                float h[8];
#pragma unroll
                for (int q = 0; q < 4; ++q) { h[q] = o0[q] + b0[q]; h[4 + q] = o1[q] + b1[q]; }
                if (MODE == 1) {
                    short8 iv = *(const short8*)(idb + (size_t)(row0 + row) * DIMS + col);
                    short8 o;
#pragma unroll
                    for (int q = 0; q < 8; ++q)
                        o[q] = (short)f2bf(fmaxf(h[q], 0.f) + bf2f((ushort)iv[q]));
                    *(short8*)(Ya + (size_t)(row0 + row) * DIMS + col) = o;
                } else {
                    float ss = 0.f;
#pragma unroll
                    for (int q = 0; q < 8; ++q) ss += h[q] * h[q];
                    ss += __shfl_xor(ss, 1);
                    ss += __shfl_xor(ss, 2);
                    ss += __shfl_xor(ss, 4);
                    ss += __shfl_xor(ss, 8);
                    float inv = 1.0f / fmaxf(sqrtf(ss), 1e-12f);
                    f32x4 o0s, o1s;
#pragma unroll
                    for (int q = 0; q < 4; ++q) { o0s[q] = h[q] * inv; o1s[q] = h[4 + q] * inv; }
                    *(f32x4*)(outf + (size_t)(row0 + row) * DIMS + col) = o0s;
                    *(f32x4*)(outf + (size_t)(row0 + row) * DIMS + col + 4) = o1s;
                }
            }
        }
    }
}

// ---------------- mean aggregation (gather + scale only) ----------------
// One wave per node; 16 lanes per edge-row (16 B/lane), 4 rows per step.

__global__ __launch_bounds__(256) void agg_mean(const ushort* __restrict__ hsrc,
                                                const int* __restrict__ row_start,
                                                const int* __restrict__ col_idx,
                                                const float* __restrict__ deg_inv,
                                                ushort* __restrict__ mean, int n) {
    const int wv = threadIdx.x >> 6;
    const int lane = threadIdx.x & 63;
    const int node = blockIdx.x * 4 + wv;
    if (node >= n) return;
    const int grp = lane >> 4;
    const int sl = lane & 15;

    const int s = row_start[node];
    const int cnt = row_start[node + 1] - s;

    float f[8] = {};
    for (int p0 = 0; p0 < cnt; p0 += 64) {
        int m = cnt - p0;
        if (m > 64) m = 64;
        int cv = (p0 + lane < cnt) ? col_idx[s + p0 + lane] : 0;
        for (int j = 0; j < m; j += 4) {
            int c = __shfl(cv, j + grp);
            if (j + grp < m) {
                short8 v = *(const short8*)(hsrc + (size_t)c * DIMS + sl * 8);
#pragma unroll
                for (int q = 0; q < 8; ++q) f[q] += bf2f((ushort)v[q]);
            }
        }
    }
#pragma unroll
    for (int q = 0; q < 8; ++q) {
        f[q] += __shfl_xor(f[q], 16);
        f[q] += __shfl_xor(f[q], 32);
    }
    if (grp == 0) {
        const float di = deg_inv[node];
        short8 o;
#pragma unroll
        for (int q = 0; q < 8; ++q) o[q] = (short)f2bf(f[q] * di);
        *(short8*)(mean + (size_t)node * DIMS + sl * 8) = o;
    }
}

// ---------------- launch ----------------

extern "C" void kernel_launch(void* const* d_in, const int* in_sizes, int n_in,
                              void* d_out, int out_size, void* d_ws, size_t ws_size,
                              hipStream_t stream) {
    const float* x     = (const float*)d_in[0];
    const int*   eidx  = (const int*)d_in[1];
    const float* Wproj = (const float*)d_in[2];
    const float* W1_l  = (const float*)d_in[3];
    const float* b1    = (const float*)d_in[4];
    const float* W1_r  = (const float*)d_in[5];
    const float* W2_l  = (const float*)d_in[6];
    const float* b2    = (const float*)d_in[7];
    const float* W2_r  = (const float*)d_in[8];
    const float* W3_l  = (const float*)d_in[9];
    const float* b3    = (const float*)d_in[10];
    const float* W3_r  = (const float*)d_in[11];
    float* out = (float*)d_out;

    const int N = in_sizes[0] / DIMS;
    const int E = in_sizes[1] / 2;
    const int* src = eidx;
    const int* dst = eidx + E;

    size_t off = 0;
    auto alloc = [&](size_t bytes) {
        void* p = (char*)d_ws + off;
        off += (bytes + 511) & ~(size_t)511;
        return p;
    };
    int*    deg_cnt   = (int*)alloc((size_t)N * 4);
    int*    cursor    = (int*)alloc((size_t)N * 4);
    int*    row_start = (int*)alloc((size_t)(N + 1) * 4);
    float*  deg_inv   = (float*)alloc((size_t)N * 4);
    int*    col_idx   = (int*)alloc((size_t)E * 4);
    int*    bsum      = (int*)alloc((size_t)1024 * 4);
    ushort* wbuf      = (ushort*)alloc((size_t)(16384 + 3 * 32768) * 2);
    ushort* xb        = (ushort*)alloc((size_t)N * DIMS * 2);
    ushort* h0        = (ushort*)alloc((size_t)N * DIMS * 2);  // reused as h2
    ushort* h1        = (ushort*)alloc((size_t)N * DIMS * 2);
    ushort* mbuf      = (ushort*)alloc((size_t)N * DIMS * 2);
    ushort* h2        = h0;
    (void)ws_size;

    hipMemsetAsync(deg_cnt, 0, (size_t)N * 4, stream);
    hipMemsetAsync(cursor, 0, (size_t)N * 4, stream);

    const int egrid = (E + 255) / 256;
    const int sgrid = (N + SCAN_B - 1) / SCAN_B;
    const int ggrid = (N + 127) / 128;
    const int agrid = (N + 3) / 4;

    const ushort* w1 = wbuf + 16384;
    const ushort* w2 = wbuf + 16384 + 32768;
    const ushort* w3 = wbuf + 16384 + 2 * 32768;

    hist_kernel<<<egrid, 256, 0, stream>>>(dst, deg_cnt, E);
    scan_reduce<<<sgrid, 256, 0, stream>>>(deg_cnt, bsum, N);
    scan_bsum<<<1, 256, 0, stream>>>(bsum, sgrid);
    scan_final<<<sgrid, 256, 0, stream>>>(deg_cnt, bsum, row_start, deg_inv, N);
    fill_kernel<<<egrid, 256, 0, stream>>>(src, dst, row_start, cursor, col_idx, E);
    wconv_kernel<<<dim3(16, 4), 256, 0, stream>>>(Wproj, W1_l, W1_r, W2_l, W2_r, W3_l, W3_r,
                                                  wbuf);

    // h0 = x @ Wproj^T ; xb = bf16(x)
    gemm_fused<0><<<ggrid, 512, 0, stream>>>(x, nullptr, wbuf, nullptr, nullptr,
                                             h0, xb, nullptr, N);

    // layer 1: m = mean(h0); h1 = relu([m|h0]@W1'^T + b1) + xb
    agg_mean<<<agrid, 256, 0, stream>>>(h0, row_start, col_idx, deg_inv, mbuf, N);
    gemm_fused<1><<<ggrid, 512, 0, stream>>>(mbuf, h0, w1, b1, xb, h1, nullptr, nullptr, N);

    // layer 2: m = mean(h1); h2 = relu([m|h1]@W2'^T + b2) + h1
    agg_mean<<<agrid, 256, 0, stream>>>(h1, row_start, col_idx, deg_inv, mbuf, N);
    gemm_fused<1><<<ggrid, 512, 0, stream>>>(mbuf, h1, w2, b2, h1, h2, nullptr, nullptr, N);

    // layer 3: m = mean(h2); out = L2norm([m|h2]@W3'^T + b3)
    agg_mean<<<agrid, 256, 0, stream>>>(h2, row_start, col_idx, deg_inv, mbuf, N);
    gemm_fused<2><<<ggrid, 512, 0, stream>>>(mbuf, h2, w3, b3, nullptr, nullptr, nullptr,
                                             out, N);
}